// Round 10
// baseline (283.722 us; speedup 1.0000x reference)
//
#include <hip/hip_runtime.h>
#include <cmath>

#define NTOK 65536
#define DMOD 1024
#define NEXP 64
#define TOPK 8
#define BTOK 64                  // tokens per block
#define KCH  64                  // k-chunk staged in LDS
#define NCH  (DMOD / KCH)
#define STR  65                  // odd stride -> conflict-free tile reads

// token_mask may arrive as 1-byte bool or int32; sniff from the first word.
__device__ __forceinline__ bool tok_mask(const void* tm, int t, int mmode) {
    return mmode == 0 ? (((const unsigned char*)tm)[t] != 0)
                      : (((const unsigned int*)tm)[t] != 0u);
}

__global__ __launch_bounds__(256, 4)
void router_v10(const float* __restrict__ h,
                const float* __restrict__ W,
                const void* __restrict__ tmask,
                float* __restrict__ out)
{
    __shared__ float h_s[BTOK][STR];          // 16.6 KB; ls aliases after compute
    __shared__ float w_s[NEXP][STR];          // 16.6 KB
    __shared__ float sm_m0[BTOK], sm_inv[BTOK];
    __shared__ unsigned long long mb[BTOK];

    const int tid  = threadIdx.x;
    const int lane = tid & 63;
    const int wave = tid >> 6;
    const int tg   = tid >> 3;                // 0..31 -> token rows 2tg, 2tg+1
    const int eg   = tid & 7;                 // expert rows 8eg..8eg+7
    const int t0   = blockIdx.x * BTOK;

    const unsigned int mw = *(const unsigned int*)tmask;
    const int mmode = (mw == 0x01010101u) ? 0 : 1;

    // strict sequential fp32 FMA per output, k ascending (np-ref-matching order)
    float acc[2][8];
#pragma unroll
    for (int i = 0; i < 2; ++i)
#pragma unroll
        for (int j = 0; j < 8; ++j) acc[i][j] = 0.f;

    const int sro = tid >> 4;                 // staging row offset 0..15
    const int sc  = (tid & 15) * 4;           // staging col 0..60

    for (int c = 0; c < NCH; ++c) {
        const int kc = c * KCH;

        // ---- stage h & W tiles: 8 independent global loads, then 8 LDS writes ----
        float4 ht[4], wt[4];
#pragma unroll
        for (int p = 0; p < 4; ++p) {
            const int row = p * 16 + sro;
            ht[p] = *reinterpret_cast<const float4*>(h + (size_t)(t0 + row) * DMOD + kc + sc);
            wt[p] = *reinterpret_cast<const float4*>(W + ((size_t)row << 10) + kc + sc);
        }
#pragma unroll
        for (int p = 0; p < 4; ++p) {
            const int row = p * 16 + sro;
            *reinterpret_cast<float4*>(&h_s[row][sc]) = ht[p];
            *reinterpret_cast<float4*>(&w_s[row][sc]) = wt[p];
        }
        __syncthreads();

        // ---- compute: 2 tokens x 8 experts; per 4-k: 10 b128 reads, 64 FMA ----
#pragma unroll 4
        for (int k4 = 0; k4 < KCH / 4; ++k4) {
            float4 hv[2], wv[8];
#pragma unroll
            for (int i = 0; i < 2; ++i)
                hv[i] = *reinterpret_cast<const float4*>(&h_s[tg * 2 + i][k4 * 4]);
#pragma unroll
            for (int j = 0; j < 8; ++j)
                wv[j] = *reinterpret_cast<const float4*>(&w_s[eg * 8 + j][k4 * 4]);
#pragma unroll
            for (int i = 0; i < 2; ++i) {
#pragma unroll
                for (int j = 0; j < 8; ++j) {
                    float a = acc[i][j];
                    a = fmaf(hv[i].x, wv[j].x, a);
                    a = fmaf(hv[i].y, wv[j].y, a);
                    a = fmaf(hv[i].z, wv[j].z, a);
                    a = fmaf(hv[i].w, wv[j].w, a);
                    acc[i][j] = a;
                }
            }
        }
        __syncthreads();
    }

    // ---- stage logits (ls aliases the dead h tile) ----
    float (*ls)[STR] = h_s;
#pragma unroll
    for (int i = 0; i < 2; ++i)
#pragma unroll
        for (int j = 0; j < 8; ++j)
            ls[tg * 2 + i][eg * 8 + j] = acc[i][j];

    __syncthreads();

    const size_t P = (size_t)NTOK * NEXP;
    float* __restrict__ o_mask = out;
    float* __restrict__ o_prob = out + P;
    float* __restrict__ o_lc   = out + 2 * P;
    float* __restrict__ o_lsl  = out + 3 * P;
    const size_t base = (size_t)t0 * NEXP;

    // ---- vectorized writes of logits_clean / logits_sel (float4) ----
#pragma unroll
    for (int p = 0; p < 4; ++p) {
        const int g  = p * 256 + tid;         // float4 index
        const int t  = g >> 4;
        const int e4 = (g & 15) * 4;
        const float4 lv = *reinterpret_cast<const float4*>(&ls[t][e4]);
        const bool tmt = tok_mask(tmask, t0 + t, mmode);
        float4 sv;
        sv.x = tmt ? lv.x : -INFINITY;
        sv.y = tmt ? lv.y : -INFINITY;
        sv.z = tmt ? lv.z : -INFINITY;
        sv.w = tmt ? lv.w : -INFINITY;
        *reinterpret_cast<float4*>(&o_lc[base + (size_t)g * 4])  = lv;
        *reinterpret_cast<float4*>(&o_lsl[base + (size_t)g * 4]) = sv;
    }

    // ---- epilogue: wave0, one token per lane; 8-pass selection-sort top-k ----
    if (wave == 0) {
        const int lt = lane;
        const bool tm = tok_mask(tmask, t0 + lt, mmode);

        unsigned long long bits = 0ULL;
        float m0 = -INFINITY;
        for (int r = 0; r < TOPK; ++r) {
            float bv = -INFINITY; int bi = 0;
            for (int e = 0; e < 64; ++e) {
                if ((bits >> e) & 1ULL) continue;
                const float x = ls[lt][e];
                if (x > bv) { bv = x; bi = e; }
            }
            bits |= 1ULL << bi;
            if (r == 0) m0 = bv;
        }

        float ssum = 0.f;
        for (int e = 0; e < 64; ++e)
            if ((bits >> e) & 1ULL) ssum += expf(ls[lt][e] - m0);

        sm_m0[lt]  = m0;
        sm_inv[lt] = 1.0f / ssum;
        mb[lt] = tm ? bits : 0ULL;            // mb==0 encodes masked token
    }

    __syncthreads();

    // ---- vectorized writes of probs / mask (float4) ----
#pragma unroll
    for (int p = 0; p < 4; ++p) {
        const int g  = p * 256 + tid;
        const int t  = g >> 4;
        const int e4 = (g & 15) * 4;
        const float4 lv = *reinterpret_cast<const float4*>(&ls[t][e4]);
        const unsigned long long bt = mb[t];
        const float m0 = sm_m0[t], inv = sm_inv[t];
        float4 pv, mv;
        const bool s0 = (bt >> (e4 + 0)) & 1ULL;
        const bool s1 = (bt >> (e4 + 1)) & 1ULL;
        const bool s2 = (bt >> (e4 + 2)) & 1ULL;
        const bool s3 = (bt >> (e4 + 3)) & 1ULL;
        pv.x = s0 ? expf(lv.x - m0) * inv : 0.f;
        pv.y = s1 ? expf(lv.y - m0) * inv : 0.f;
        pv.z = s2 ? expf(lv.z - m0) * inv : 0.f;
        pv.w = s3 ? expf(lv.w - m0) * inv : 0.f;
        mv.x = s0 ? 1.f : 0.f;
        mv.y = s1 ? 1.f : 0.f;
        mv.z = s2 ? 1.f : 0.f;
        mv.w = s3 ? 1.f : 0.f;
        *reinterpret_cast<float4*>(&o_prob[base + (size_t)g * 4]) = pv;
        *reinterpret_cast<float4*>(&o_mask[base + (size_t)g * 4]) = mv;
    }
}

extern "C" void kernel_launch(void* const* d_in, const int* in_sizes, int n_in,
                              void* d_out, int out_size, void* d_ws, size_t ws_size,
                              hipStream_t stream)
{
    const float* h = (const float*)d_in[0];
    const float* W = (const float*)d_in[1];
    const void*  tmask = (const void*)d_in[2];
    float* out = (float*)d_out;

    hipLaunchKernelGGL(router_v10, dim3(NTOK / BTOK), dim3(256), 0, stream,
                       h, W, tmask, out);
}

// Round 11
// 229.730 us; speedup vs baseline: 1.2350x; 1.2350x over previous
//
#include <hip/hip_runtime.h>
#include <cmath>

#define NTOK 65536
#define DMOD 1024
#define NEXP 64
#define TOPK 8
#define BTOK 64                  // tokens per block
#define KCH  64                  // k-chunk staged in LDS
#define NCH  (DMOD / KCH)
#define STR  65                  // odd stride -> conflict-free tile reads

// token_mask may arrive as 1-byte bool or int32; sniff from the first word.
__device__ __forceinline__ bool tok_mask(const void* tm, int t, int mmode) {
    return mmode == 0 ? (((const unsigned char*)tm)[t] != 0)
                      : (((const unsigned int*)tm)[t] != 0u);
}

__global__ __launch_bounds__(256, 4)
void router_v11(const float* __restrict__ h,
                const float* __restrict__ W,
                const void* __restrict__ tmask,
                float* __restrict__ out)
{
    __shared__ float h_s[BTOK][STR];          // 16.6 KB
    __shared__ float w_s[NEXP][STR];          // 16.6 KB; ls aliases after compute
    __shared__ float sm_m0[BTOK], sm_inv[BTOK];
    __shared__ unsigned long long mb[BTOK];

    const int tid  = threadIdx.x;
    const int lane = tid & 63;
    const int wave = tid >> 6;
    const int tt   = tid & 15;                // token group: rows 4tt..4tt+3
    const int ee   = tid >> 4;                // expert group: rows 4ee..4ee+3
    const int t0   = blockIdx.x * BTOK;

    const unsigned int mw = *(const unsigned int*)tmask;
    const int mmode = (mw == 0x01010101u) ? 0 : 1;

    // strict sequential fp32 FMA per output, k ascending (np-ref-matching order)
    float acc[4][4];
#pragma unroll
    for (int i = 0; i < 4; ++i)
#pragma unroll
        for (int j = 0; j < 4; ++j) acc[i][j] = 0.f;

    const int sr = tid >> 4;                  // staging row offset 0..15
    const int sc = (tid & 15) * 4;            // staging col 0..60

#define LOAD_WIN(hv, wv, k4)                                                        \
    do {                                                                            \
        _Pragma("unroll")                                                           \
        for (int i = 0; i < 4; ++i)                                                 \
            hv[i] = *reinterpret_cast<const float4*>(&h_s[tt * 4 + i][(k4) * 4]);   \
        _Pragma("unroll")                                                           \
        for (int j = 0; j < 4; ++j)                                                 \
            wv[j] = *reinterpret_cast<const float4*>(&w_s[ee * 4 + j][(k4) * 4]);   \
    } while (0)

#define FMA_WIN(hv, wv)                                                             \
    do {                                                                            \
        _Pragma("unroll")                                                           \
        for (int i = 0; i < 4; ++i) {                                               \
            _Pragma("unroll")                                                       \
            for (int j = 0; j < 4; ++j) {                                           \
                float a = acc[i][j];                                                \
                a = fmaf(hv[i].x, wv[j].x, a);                                      \
                a = fmaf(hv[i].y, wv[j].y, a);                                      \
                a = fmaf(hv[i].z, wv[j].z, a);                                      \
                a = fmaf(hv[i].w, wv[j].w, a);                                      \
                acc[i][j] = a;                                                      \
            }                                                                       \
        }                                                                           \
    } while (0)

    for (int c = 0; c < NCH; ++c) {
        const int kc = c * KCH;

        // ---- stage h & W tiles: 8 independent global loads, then 8 LDS writes ----
        float4 ht[4], wt[4];
#pragma unroll
        for (int p = 0; p < 4; ++p) {
            const int row = p * 16 + sr;
            ht[p] = *reinterpret_cast<const float4*>(h + (size_t)(t0 + row) * DMOD + kc + sc);
            wt[p] = *reinterpret_cast<const float4*>(W + ((size_t)row << 10) + kc + sc);
        }
#pragma unroll
        for (int p = 0; p < 4; ++p) {
            const int row = p * 16 + sr;
            *reinterpret_cast<float4*>(&h_s[row][sc]) = ht[p];
            *reinterpret_cast<float4*>(&w_s[row][sc]) = wt[p];
        }
        __syncthreads();

        // ---- compute: software-pipelined operand double-buffer (A/B reg sets) ----
        float4 hA[4], wA[4], hB[4], wB[4];
        LOAD_WIN(hA, wA, 0);
#pragma unroll
        for (int k4 = 0; k4 < KCH / 4; k4 += 2) {
            if (k4 + 1 < KCH / 4) LOAD_WIN(hB, wB, k4 + 1);   // prefetch next window
            FMA_WIN(hA, wA);                                   // compute current
            if (k4 + 2 < KCH / 4) LOAD_WIN(hA, wA, k4 + 2);   // prefetch window+2
            FMA_WIN(hB, wB);
        }
        __syncthreads();
    }

    // ---- stage logits (ls aliases the dead w_s tile) ----
    float (*ls)[STR] = w_s;
#pragma unroll
    for (int i = 0; i < 4; ++i)
#pragma unroll
        for (int j = 0; j < 4; ++j)
            ls[tt * 4 + i][ee * 4 + j] = acc[i][j];

    __syncthreads();

    const size_t P = (size_t)NTOK * NEXP;
    float* __restrict__ o_mask = out;
    float* __restrict__ o_prob = out + P;
    float* __restrict__ o_lc   = out + 2 * P;
    float* __restrict__ o_lsl  = out + 3 * P;
    const size_t base = (size_t)t0 * NEXP;

    // ---- vectorized writes of logits_clean / logits_sel (float4) ----
#pragma unroll
    for (int p = 0; p < 4; ++p) {
        const int g  = p * 256 + tid;         // float4 index
        const int t  = g >> 4;
        const int e4 = (g & 15) * 4;
        const float4 lv = *reinterpret_cast<const float4*>(&ls[t][e4]);
        const bool tmt = tok_mask(tmask, t0 + t, mmode);
        float4 sv;
        sv.x = tmt ? lv.x : -INFINITY;
        sv.y = tmt ? lv.y : -INFINITY;
        sv.z = tmt ? lv.z : -INFINITY;
        sv.w = tmt ? lv.w : -INFINITY;
        *reinterpret_cast<float4*>(&o_lc[base + (size_t)g * 4])  = lv;
        *reinterpret_cast<float4*>(&o_lsl[base + (size_t)g * 4]) = sv;
    }

    // ---- epilogue: wave0, one token per lane; 8-pass selection-sort top-k ----
    if (wave == 0) {
        const int lt = lane;
        const bool tm = tok_mask(tmask, t0 + lt, mmode);

        unsigned long long bits = 0ULL;
        float m0 = -INFINITY;
        for (int r = 0; r < TOPK; ++r) {
            float bv = -INFINITY; int bi = 0;
            for (int e = 0; e < 64; ++e) {
                if ((bits >> e) & 1ULL) continue;
                const float x = ls[lt][e];
                if (x > bv) { bv = x; bi = e; }
            }
            bits |= 1ULL << bi;
            if (r == 0) m0 = bv;
        }

        float ssum = 0.f;
        for (int e = 0; e < 64; ++e)
            if ((bits >> e) & 1ULL) ssum += expf(ls[lt][e] - m0);

        sm_m0[lt]  = m0;
        sm_inv[lt] = 1.0f / ssum;
        mb[lt] = tm ? bits : 0ULL;            // mb==0 encodes masked token
    }

    __syncthreads();

    // ---- vectorized writes of probs / mask (float4) ----
#pragma unroll
    for (int p = 0; p < 4; ++p) {
        const int g  = p * 256 + tid;
        const int t  = g >> 4;
        const int e4 = (g & 15) * 4;
        const float4 lv = *reinterpret_cast<const float4*>(&ls[t][e4]);
        const unsigned long long bt = mb[t];
        const float m0 = sm_m0[t], inv = sm_inv[t];
        float4 pv, mv;
        const bool s0 = (bt >> (e4 + 0)) & 1ULL;
        const bool s1 = (bt >> (e4 + 1)) & 1ULL;
        const bool s2 = (bt >> (e4 + 2)) & 1ULL;
        const bool s3 = (bt >> (e4 + 3)) & 1ULL;
        pv.x = s0 ? expf(lv.x - m0) * inv : 0.f;
        pv.y = s1 ? expf(lv.y - m0) * inv : 0.f;
        pv.z = s2 ? expf(lv.z - m0) * inv : 0.f;
        pv.w = s3 ? expf(lv.w - m0) * inv : 0.f;
        mv.x = s0 ? 1.f : 0.f;
        mv.y = s1 ? 1.f : 0.f;
        mv.z = s2 ? 1.f : 0.f;
        mv.w = s3 ? 1.f : 0.f;
        *reinterpret_cast<float4*>(&o_prob[base + (size_t)g * 4]) = pv;
        *reinterpret_cast<float4*>(&o_mask[base + (size_t)g * 4]) = mv;
    }
}

extern "C" void kernel_launch(void* const* d_in, const int* in_sizes, int n_in,
                              void* d_out, int out_size, void* d_ws, size_t ws_size,
                              hipStream_t stream)
{
    const float* h = (const float*)d_in[0];
    const float* W = (const float*)d_in[1];
    const void*  tmask = (const void*)d_in[2];
    float* out = (float*)d_out;

    hipLaunchKernelGGL(router_v11, dim3(NTOK / BTOK), dim3(256), 0, stream,
                       h, W, tmask, out);
}